// Round 14
// baseline (250.474 us; speedup 1.0000x reference)
//
#include <hip/hip_runtime.h>
#include <math.h>

#define Bb 4
#define Lq 384
#define Dm 512
#define Hh 8
#define Kk 64
#define Ff 2048
#define Mm 512
#define NLAY 2
#define NDb 15
#define BL (Bb*Lq)
#define QKVLD 1536
#define KeROWS 448          // 384 keys + 15 de0 rows + zero pad
#define EP 460              // E LDS pitch (dwords): 460%32=12 -> conflict-light
#define PPs 920             // P LDS pitch (shorts), aliases E rows
#define LWP 17              // lw pitch (floats)
#define QR 16               // q-rows per attn block

typedef __attribute__((ext_vector_type(8))) short bfrag;
typedef __attribute__((ext_vector_type(4))) float f32x4;
typedef __attribute__((ext_vector_type(4))) short short4v;
typedef __attribute__((ext_vector_type(2))) unsigned int uint2v;
typedef unsigned int uint;
typedef unsigned char uchar;

__device__ __forceinline__ short f2b(float f) {
    unsigned u = __builtin_bit_cast(unsigned, f);
    unsigned r = (u + 0x7fffu + ((u >> 16) & 1u)) >> 16;
    return (short)r;
}
__device__ __forceinline__ float b2f(short s) {
    unsigned u = ((unsigned)(unsigned short)s) << 16;
    return __builtin_bit_cast(float, u);
}

// =============== prologue mega-kernel (all independent prep work) ===============
__device__ __forceinline__ void tile_tr(const float* __restrict__ src, short* __restrict__ dst,
                                        int Kd, int N, int t, int tx, int ty) {
    __shared__ float ts[32][33];
    int nt = t % (N / 32), kt = t / (N / 32);
    int n0 = nt * 32, k0 = kt * 32;
    for (int i = ty; i < 32; i += 8) ts[i][tx] = src[(size_t)(k0 + i) * N + n0 + tx];
    __syncthreads();
    for (int i = ty; i < 32; i += 8) dst[(size_t)(n0 + i) * Kd + k0 + tx] = f2b(ts[tx][i]);
}

__global__ __launch_bounds__(256) void prologue_all(
        const int* __restrict__ ct, const float* __restrict__ cell_emb,
        const float* __restrict__ dist, const float* __restrict__ de,
        const float* __restrict__ bq, const float* __restrict__ bk, const float* __restrict__ bv,
        const float* __restrict__ Wq, const float* __restrict__ Wk,
        const float* __restrict__ Wv, const float* __restrict__ Wo,
        const float* __restrict__ W1, const float* __restrict__ W2,
        const float* __restrict__ Wm1,
        float* __restrict__ h, short* __restrict__ hb,
        uchar* __restrict__ didx8, int* __restrict__ dr, float* __restrict__ qkvb,
        short* __restrict__ Ke, short* __restrict__ Wt_all, short* __restrict__ Wm1T) {
    const size_t WLAY = 4ull * Dm * Dm + (size_t)Dm * Ff + (size_t)Ff * Dm;
    int blk = blockIdx.x, tid = threadIdx.x;
    if (blk < 576) {                        // didx: 4 elems/thread, packed bytes
        int i = blk * 256 + tid;
        f32x4 d = *(const f32x4*)(dist + (size_t)i * 4);
        uint r = 0;
#pragma unroll
        for (int c = 0; c < 4; ++c) {
            int cnt = 0;
#pragma unroll
            for (int q = 1; q <= 14; ++q) cnt += (float)(10 * q) < d[c] ? 1 : 0;
            r |= (uint)cnt << (8 * c);
        }
        ((uint*)didx8)[i] = r;
    } else if (blk < 582) {                 // dr (from dist[b][0][x] directly)
        int i = (blk - 576) * 256 + tid;
        if (i < BL) {
            int b = i / Lq, x = i % Lq;
            float d = dist[(size_t)b * Lq * Lq + x];
            int c = 0;
#pragma unroll
            for (int q = 1; q <= 14; ++q) c += (float)(10 * q) < d ? 1 : 0;
            dr[i] = c;
        }
    } else if (blk < 3654) {                // embed
        int i = (blk - 582) * 256 + tid;
        int row = i / Dm, d = i % Dm;
        float v = cell_emb[ct[row] * Dm + d];
        h[i] = v;
        hb[i] = f2b(v);
    } else if (blk < 3666) {                // qkv bias concat
        int i = (blk - 3654) * 256 + tid;
        int l = i / QKVLD, c = i % QKVLD;
        float v = (c < Dm) ? bq[l * Dm + c] : (c < 2 * Dm) ? bk[l * Dm + c - Dm] : bv[l * Dm + c - 2 * Dm];
        qkvb[i] = v;
    } else if (blk < 4178) {                // Ke tail: de0 rows + zeros
        int i = (blk - 3666) * 256 + tid;   // 32*64*64
        int k = i & 63, rr = (i >> 6) & 63, z = i >> 12;
        short v = (rr < NDb) ? f2b(de[rr * Kk + k]) : (short)0;
        Ke[((size_t)z * KeROWS + Lq + rr) * Kk + k] = v;
    } else {                                // weight transposes
        int idx = blk - 4178;
        int tx = tid & 31, ty = tid >> 5;
        if (idx < 2048) {
            int m4 = idx >> 9, rem = idx & 511, l = rem >> 8, t = rem & 255;
            const float* src = (m4 == 0 ? Wq : m4 == 1 ? Wk : m4 == 2 ? Wv : Wo) + (size_t)l * Dm * Dm;
            tile_tr(src, Wt_all + l * WLAY + (size_t)m4 * Dm * Dm, Dm, Dm, t, tx, ty);
        } else if (idx < 4096) {
            int rem = idx - 2048, l = rem >> 10, t = rem & 1023;
            tile_tr(W1 + (size_t)l * Dm * Ff, Wt_all + l * WLAY + 4ull * Dm * Dm, Dm, Ff, t, tx, ty);
        } else if (idx < 6144) {
            int rem = idx - 4096, l = rem >> 10, t = rem & 1023;
            tile_tr(W2 + (size_t)l * Ff * Dm, Wt_all + l * WLAY + 4ull * Dm * Dm + (size_t)Dm * Ff, Ff, Dm, t, tx, ty);
        } else {
            tile_tr(Wm1, Wm1T, Dm, Mm, idx - 6144, tx, ty);
        }
    }
}

// =============== QKV GEMM (32x64 tile, 2-wave K-split) + fused K/V prep ===============
// Vet (V^T) stores are v-packed: the 4 accumulator v-values are consecutive x,
// so one short4v (8B) store replaces 4 scattered 2B stores.
__global__ __launch_bounds__(128) void qkv_gemm(const short* __restrict__ A,
                                                const short* __restrict__ Bt,
                                                const float* __restrict__ bias,
                                                const int* __restrict__ dr,
                                                const float* __restrict__ de,
                                                short* __restrict__ Qb,
                                                short* __restrict__ Ke,
                                                short* __restrict__ Vet) {
    const int tid = threadIdx.x;
    const int wave = tid >> 6, lane = tid & 63;
    const int row0 = blockIdx.y * 32, col0 = blockIdx.x * 64;
    const int r = lane & 15, g = lane >> 4;
    const int kbase = wave * (Dm / 2);
    __shared__ float red[64][33];
    f32x4 acc[2][4] = {};
#pragma unroll 4
    for (int k0 = 0; k0 < Dm / 2; k0 += 32) {
        bfrag a[2], b[4];
#pragma unroll
        for (int i = 0; i < 2; ++i)
            a[i] = *(const bfrag*)(A + (size_t)(row0 + i * 16 + r) * Dm + kbase + k0 + g * 8);
#pragma unroll
        for (int j = 0; j < 4; ++j)
            b[j] = *(const bfrag*)(Bt + (size_t)(col0 + j * 16 + r) * Dm + kbase + k0 + g * 8);
#pragma unroll
        for (int i = 0; i < 2; ++i)
#pragma unroll
            for (int j = 0; j < 4; ++j)
                acc[i][j] = __builtin_amdgcn_mfma_f32_16x16x32_bf16(a[i], b[j], acc[i][j], 0, 0, 0);
    }
    if (wave == 1) {
#pragma unroll
        for (int i = 0; i < 2; ++i)
#pragma unroll
            for (int j = 0; j < 4; ++j)
#pragma unroll
                for (int v = 0; v < 4; ++v)
                    red[lane][(i * 4 + j) * 4 + v] = acc[i][j][v];
    }
    __syncthreads();
    if (wave != 0) return;
#pragma unroll
    for (int i = 0; i < 2; ++i)
#pragma unroll
        for (int j = 0; j < 4; ++j)
#pragma unroll
            for (int v = 0; v < 4; ++v)
                acc[i][j][v] += red[lane][(i * 4 + j) * 4 + v];
    const float* de2 = de + 2 * NDb * Kk;
    const float* de5 = de + 5 * NDb * Kk;
    if (col0 < 2 * Dm) {
        // ---- Q / K region: stores already coalesced in 32B runs ----
#pragma unroll
        for (int i = 0; i < 2; ++i)
#pragma unroll
            for (int v = 0; v < 4; ++v) {
                int row = row0 + i * 16 + g * 4 + v;
                int b = row / Lq, x = row - b * Lq;
                int dd = dr[row];
#pragma unroll
                for (int j = 0; j < 4; ++j) {
                    int col = col0 + j * 16 + r;
                    float val = acc[i][j][v] + bias[col];
                    if (col < Dm) {
                        Qb[(size_t)row * Dm + col] = f2b(val);
                    } else {
                        int k = col & 63, h2 = (col >> 6) & 7, z = b * Hh + h2;
                        Ke[((size_t)z * KeROWS + x) * Kk + k] = f2b(val + de2[dd * Kk + k]);
                    }
                }
            }
    } else {
        // ---- V region: v-packed 8B stores (4 consecutive x per thread) ----
        int h2 = (col0 >> 6) & 7;
#pragma unroll
        for (int i = 0; i < 2; ++i) {
            int rowb = row0 + i * 16 + g * 4;        // 32-row tile within one b
            int b = rowb / Lq;
            int x0 = rowb - b * Lq;
            int z = b * Hh + h2;
            int dd[4];
#pragma unroll
            for (int v = 0; v < 4; ++v) dd[v] = dr[rowb + v];
#pragma unroll
            for (int j = 0; j < 4; ++j) {
                int k = j * 16 + r;                  // col0 is a multiple of 64
                float bc = bias[col0 + j * 16 + r];
                short4v pk4;
#pragma unroll
                for (int v = 0; v < 4; ++v)
                    pk4[v] = f2b(acc[i][j][v] + bc + de5[dd[v] * Kk + k]);
                *(short4v*)(Vet + ((size_t)z * Kk + k) * Lq + x0) = pk4;
            }
        }
    }
}

// =============== fused flash attention (8 waves, per 16 q-rows x one (b,h)) ===============
// 768 blocks x 512 thr; XCD x = n&7 owns z in {4x..4x+3} -> Ke/Vet L2-resident.
__global__ __launch_bounds__(512) void attn_fused(const short* __restrict__ Qb,
                                                  const short* __restrict__ Ke,
                                                  const short* __restrict__ Vet,
                                                  const uchar* __restrict__ didx8,
                                                  const int* __restrict__ dr,
                                                  const float* __restrict__ de,
                                                  short* __restrict__ Zb) {
    const int n = blockIdx.x;
    const int xcd = n & 7, kblk = n >> 3;       // kblk in [0,96)
    const int z = xcd * 4 + (kblk & 3);
    const int qt = kblk >> 2;                   // [0,24) tiles of 16 rows
    const int b = z >> 3, hh = z & 7;
    const int tid = threadIdx.x;
    const int wave = tid >> 6, lane = tid & 63;
    const int r = lane & 15, g = lane >> 4;
    __shared__ float Ef[QR * EP];
    __shared__ float lw[QR * LWP];
    __shared__ float invrow[QR];
    __shared__ float pred[4][64][5];            // PV partial reduce, padded

    // ---- hoisted didx loads (packed uint8, 12B = 3x uint per thread) ----
    const int row = tid >> 5, s32 = tid & 31;
    const int grow = qt * QR + row;
    const uchar* dxp = didx8 + ((size_t)(b * Lq + grow)) * Lq + s32 * 12;
    uint w0 = *(const uint*)(dxp);
    uint w1 = *(const uint*)(dxp + 4);
    uint w2 = *(const uint*)(dxp + 8);

    // ---- phase 1: E = Q @ Ke^T into LDS (cols 384.. hold q.de0[j]) ----
    const short* Qbase = Qb + ((size_t)(b * Lq + qt * QR)) * Dm + hh * Kk;
    const short* Kbase = Ke + (size_t)z * KeROWS * Kk;
    f32x4 eacc[2][2] = {};
#pragma unroll
    for (int k0 = 0; k0 < Kk; k0 += 32) {
        bfrag a = *(const bfrag*)(Qbase + (size_t)r * Dm + k0 + g * 8);
#pragma unroll
        for (int t = 0; t < 2; ++t) {
            int ctile = wave + t * 8;
            if (ctile < 14) {
                bfrag bb[2];
#pragma unroll
                for (int i = 0; i < 2; ++i)
                    bb[i] = *(const bfrag*)(Kbase + (size_t)(ctile * 32 + i * 16 + r) * Kk + k0 + g * 8);
#pragma unroll
                for (int j = 0; j < 2; ++j)
                    eacc[t][j] = __builtin_amdgcn_mfma_f32_16x16x32_bf16(a, bb[j], eacc[t][j], 0, 0, 0);
            }
        }
    }
#pragma unroll
    for (int t = 0; t < 2; ++t) {
        int ctile = wave + t * 8;
        if (ctile < 14) {
#pragma unroll
            for (int j = 0; j < 2; ++j)
#pragma unroll
                for (int v = 0; v < 4; ++v)
                    Ef[(g * 4 + v) * EP + ctile * 32 + j * 16 + r] = eacc[t][j][v];
        }
    }
    __syncthreads();

    // ---- phase 2: softmax (32 threads per row, 12 keys each, reg-cached) ----
    float* Er = Ef + row * EP;
    uint dxw[3] = {w0, w1, w2};
    float sv[12];
    float mx = -1e30f;
#pragma unroll
    for (int u = 0; u < 3; ++u) {
        f32x4 ev = *(const f32x4*)(Er + s32 * 12 + u * 4);
        uint w = dxw[u];
#pragma unroll
        for (int c = 0; c < 4; ++c) {
            int dxv = (w >> (8 * c)) & 255;
            float s = ev[c] + Er[Lq + dxv];
            sv[u * 4 + c] = s;
            mx = fmaxf(mx, s);
        }
    }
    mx = fmaxf(mx, __shfl_xor(mx, 1));
    mx = fmaxf(mx, __shfl_xor(mx, 2));
    mx = fmaxf(mx, __shfl_xor(mx, 4));
    mx = fmaxf(mx, __shfl_xor(mx, 8));
    mx = fmaxf(mx, __shfl_xor(mx, 16));
    float sum = 0.f;
    float bins[NDb];
#pragma unroll
    for (int q = 0; q < NDb; ++q) bins[q] = 0.f;
#pragma unroll
    for (int u = 0; u < 3; ++u) {
        uint w = dxw[u];
#pragma unroll
        for (int c = 0; c < 4; ++c) {
            int dxv = (w >> (8 * c)) & 255;
            float e = __expf(sv[u * 4 + c] - mx);
            sv[u * 4 + c] = e;
            sum += e;
#pragma unroll
            for (int q = 0; q < NDb; ++q) bins[q] += (dxv == q) ? e : 0.f;
        }
    }
    sum += __shfl_xor(sum, 1);
    sum += __shfl_xor(sum, 2);
    sum += __shfl_xor(sum, 4);
    sum += __shfl_xor(sum, 8);
    sum += __shfl_xor(sum, 16);
#pragma unroll
    for (int q = 0; q < NDb; ++q) {
        bins[q] += __shfl_xor(bins[q], 1);
        bins[q] += __shfl_xor(bins[q], 2);
        bins[q] += __shfl_xor(bins[q], 4);
        bins[q] += __shfl_xor(bins[q], 8);
        bins[q] += __shfl_xor(bins[q], 16);
    }
    float inv = 1.0f / sum;
    if (s32 == 0) {
        invrow[row] = inv;
#pragma unroll
        for (int q = 0; q < NDb; ++q) lw[row * LWP + q] = bins[q];
    }
    uint pk[6];
#pragma unroll
    for (int i = 0; i < 6; ++i) {
        uint lo = (unsigned short)f2b(sv[2 * i] * inv);
        uint hi = (unsigned short)f2b(sv[2 * i + 1] * inv);
        pk[i] = lo | (hi << 16);
    }
    __syncthreads();   // all E reads done -> safe to overwrite with bf16 P
    uint* prow = (uint*)((short*)Ef + row * PPs + s32 * 12);
#pragma unroll
    for (int i = 0; i < 6; ++i) prow[i] = pk[i];
    __syncthreads();

    // ---- phase 3: PV K-split (pair w,w+4 -> cols [w4*16,w4*16+16)) ----
    const int half = wave >> 2, w4 = wave & 3;
    const short* Ps = (const short*)Ef;
    const short* brow = Vet + (size_t)z * Kk * Lq + (size_t)(w4 * 16 + r) * Lq;
    const int kv0 = half * (Lq / 2);
    f32x4 pacc = {};
#pragma unroll
    for (int k0 = 0; k0 < Lq / 2; k0 += 32) {
        bfrag bb = *(const bfrag*)(brow + kv0 + k0 + g * 8);
        bfrag a = *(const bfrag*)(Ps + (size_t)r * PPs + kv0 + k0 + g * 8);
        pacc = __builtin_amdgcn_mfma_f32_16x16x32_bf16(a, bb, pacc, 0, 0, 0);
    }
    if (half == 1) {
#pragma unroll
        for (int v = 0; v < 4; ++v) pred[w4][lane][v] = pacc[v];
    }
    __syncthreads();
    if (half == 1) return;
#pragma unroll
    for (int v = 0; v < 4; ++v) pacc[v] += pred[w4][lane][v];
    const float* de3 = de + 3 * NDb * Kk;
    const float* de4 = de + 4 * NDb * Kk;
    const int k = w4 * 16 + r;
    float d3[NDb];
#pragma unroll
    for (int q = 0; q < NDb; ++q) d3[q] = de3[q * Kk + k];
#pragma unroll
    for (int v = 0; v < 4; ++v) {
        int lrow = g * 4 + v;
        int gr = qt * QR + lrow;
        float wsv = 0.f;
#pragma unroll
        for (int q = 0; q < NDb; ++q) wsv += lw[lrow * LWP + q] * d3[q];
        int dd = dr[b * Lq + gr];
        float val = pacc[v] + wsv * invrow[lrow] + de4[dd * Kk + k];
        Zb[((size_t)(b * Lq + gr)) * Dm + hh * Kk + k] = f2b(val);
    }
}

// =============== generic MFMA GEMM with KW-wave K-split ===============
template <int ACT, int OUTBF, int KD, int CT, int KW>
__global__ __launch_bounds__(64 * KW) void mfma_gemm(const short* __restrict__ A,
                                                     const short* __restrict__ Bt,
                                                     const float* __restrict__ bias,
                                                     void* __restrict__ Cv,
                                                     int lda, int ldb, int ldc) {
    const int tid = threadIdx.x;
    const int wave = tid >> 6, lane = tid & 63;
    const int row0 = blockIdx.y * 32, col0 = blockIdx.x * (16 * CT);
    const int r = lane & 15, g = lane >> 4;
    const int KC = KD / KW;
    const int kbase = wave * KC;
    __shared__ float red[KW > 1 ? KW - 1 : 1][64][2 * CT * 4 + 1];
    f32x4 acc[2][CT] = {};
#pragma unroll 4
    for (int k0 = 0; k0 < KC; k0 += 32) {
        bfrag a[2], b[CT];
#pragma unroll
        for (int i = 0; i < 2; ++i)
            a[i] = *(const bfrag*)(A + (size_t)(row0 + i * 16 + r) * lda + kbase + k0 + g * 8);
#pragma unroll
        for (int j = 0; j < CT; ++j)
            b[j] = *(const bfrag*)(Bt + (size_t)(col0 + j * 16 + r) * ldb + kbase + k0 + g * 8);
#pragma unroll
        for (int i = 0; i < 2; ++i)
#pragma unroll
            for (int j = 0; j < CT; ++j)
                acc[i][j] = __builtin_amdgcn_mfma_f32_16x16x32_bf16(a[i], b[j], acc[i][j], 0, 0, 0);
    }
    if (KW > 1) {
        if (wave > 0) {
#pragma unroll
            for (int i = 0; i < 2; ++i)
#pragma unroll
                for (int j = 0; j < CT; ++j)
#pragma unroll
                    for (int v = 0; v < 4; ++v)
                        red[wave - 1][lane][(i * CT + j) * 4 + v] = acc[i][j][v];
        }
        __syncthreads();
        if (wave != 0) return;
#pragma unroll
        for (int w = 0; w < KW - 1; ++w)
#pragma unroll
            for (int i = 0; i < 2; ++i)
#pragma unroll
                for (int j = 0; j < CT; ++j)
#pragma unroll
                    for (int v = 0; v < 4; ++v)
                        acc[i][j][v] += red[w][lane][(i * CT + j) * 4 + v];
    }
#pragma unroll
    for (int i = 0; i < 2; ++i)
#pragma unroll
        for (int j = 0; j < CT; ++j)
#pragma unroll
            for (int v = 0; v < 4; ++v) {
                int row = row0 + i * 16 + g * 4 + v;
                int col = col0 + j * 16 + r;
                float val = acc[i][j][v] + bias[col];
                if (ACT == 1) val = 0.5f * val * (1.0f + erff(val * 0.7071067811865475f));
                if (OUTBF) ((short*)Cv)[(size_t)row * ldc + col] = f2b(val);
                else       ((float*)Cv)[(size_t)row * ldc + col] = val;
            }
}

// =============== residual add + LayerNorm (2 barriers, vectorized) ===============
__global__ __launch_bounds__(128) void add_ln_kernel(float* __restrict__ h,
                                                     short* __restrict__ hb,
                                                     const float* __restrict__ delta,
                                                     const float* __restrict__ g,
                                                     const float* __restrict__ be) {
    const int row = blockIdx.x, t = threadIdx.x;
    const int lane = t & 63, wid = t >> 6;
    __shared__ float red[4];
    f32x4 x = *(const f32x4*)(h + (size_t)row * Dm + t * 4);
    f32x4 d = *(const f32x4*)(delta + (size_t)row * Dm + t * 4);
    x = x + d;
    float s = x[0] + x[1] + x[2] + x[3];
#pragma unroll
    for (int o = 32; o >= 1; o >>= 1) s += __shfl_xor(s, o);
    if (lane == 0) red[wid] = s;
    __syncthreads();
    float mu = (red[0] + red[1]) * (1.0f / 512.0f);
    f32x4 dif;
    float vs = 0.f;
#pragma unroll
    for (int c = 0; c < 4; ++c) { dif[c] = x[c] - mu; vs += dif[c] * dif[c]; }
#pragma unroll
    for (int o = 32; o >= 1; o >>= 1) vs += __shfl_xor(vs, o);
    if (lane == 0) red[wid + 2] = vs;
    __syncthreads();
    float rstd = rsqrtf((red[2] + red[3]) * (1.0f / 512.0f) + 1e-5f);
    f32x4 gg = *(const f32x4*)(g + t * 4);
    f32x4 bb = *(const f32x4*)(be + t * 4);
    f32x4 y;
    short4v yb;
#pragma unroll
    for (int c = 0; c < 4; ++c) { y[c] = dif[c] * rstd * gg[c] + bb[c]; yb[c] = f2b(y[c]); }
    *(f32x4*)(h + (size_t)row * Dm + t * 4) = y;
    *(short4v*)(hb + (size_t)row * Dm + t * 4) = yb;
}

// =============== fused head: pool + MLP + final reduce (one block per b) ===============
// Replaces pool_partial + head_mlp + final_kernel (3 dispatches -> 1).
__global__ __launch_bounds__(256) void head_all(const float* __restrict__ h,
                                                const float* __restrict__ mask,
                                                const short* __restrict__ Wm1T,
                                                const float* __restrict__ bm1,
                                                const float* __restrict__ Wm2,
                                                const float* __restrict__ bm2,
                                                float* __restrict__ out) {
    const int b = blockIdx.x, tid = threadIdx.x;
    __shared__ float pooled[Mm];
    __shared__ float red[4];
    // phase A: pooled[d] = sum_l h[b,l,d] * mask[b,l]  (2 d-columns per thread)
    float s0 = 0.f, s1 = 0.f;
    const float* hbp = h + (size_t)b * Lq * Dm;
    const float* mbp = mask + b * Lq;
    for (int l = 0; l < Lq; ++l) {
        float mk = mbp[l];
        const float* hr = hbp + (size_t)l * Dm;
        s0 += hr[tid] * mk;
        s1 += hr[tid + 256] * mk;
    }
    pooled[tid] = s0;
    pooled[tid + 256] = s1;
    __syncthreads();
    // phase B: 2 output features per thread, vectorized bf16 weight loads
    float acc2 = 0.f;
#pragma unroll
    for (int half = 0; half < 2; ++half) {
        int m = tid + half * 256;
        const short* wr = Wm1T + (size_t)m * Dm;
        float a = 0.f;
        for (int k = 0; k < Dm; k += 8) {
            bfrag w8 = *(const bfrag*)(wr + k);
#pragma unroll
            for (int i = 0; i < 8; ++i) a += pooled[k + i] * b2f(w8[i]);
        }
        acc2 += fmaxf(a + bm1[m], 0.f) * Wm2[m];
    }
    // phase C: block reduce 256 partial sums -> out[b]
    const int lane = tid & 63, wid = tid >> 6;
    float v = acc2;
#pragma unroll
    for (int off = 32; off >= 1; off >>= 1) v += __shfl_xor(v, off);
    if (lane == 0) red[wid] = v;
    __syncthreads();
    if (tid == 0) out[b] = red[0] + red[1] + red[2] + red[3] + bm2[0];
}

extern "C" void kernel_launch(void* const* d_in, const int* in_sizes, int n_in,
                              void* d_out, int out_size, void* d_ws, size_t ws_size,
                              hipStream_t stream) {
    const int* ct        = (const int*)d_in[0];
    const float* dist    = (const float*)d_in[1];
    const float* mask    = (const float*)d_in[2];
    const float* cellemb = (const float*)d_in[3];
    const float* de      = (const float*)d_in[4];
    const float* Wq = (const float*)d_in[5];
    const float* bq = (const float*)d_in[6];
    const float* Wk = (const float*)d_in[7];
    const float* bk = (const float*)d_in[8];
    const float* Wv = (const float*)d_in[9];
    const float* bv = (const float*)d_in[10];
    const float* Wo = (const float*)d_in[11];
    const float* bo = (const float*)d_in[12];
    const float* W1 = (const float*)d_in[13];
    const float* b1 = (const float*)d_in[14];
    const float* W2 = (const float*)d_in[15];
    const float* b2 = (const float*)d_in[16];
    const float* g1 = (const float*)d_in[17];
    const float* be1 = (const float*)d_in[18];
    const float* g2 = (const float*)d_in[19];
    const float* be2 = (const float*)d_in[20];
    const float* Wm1 = (const float*)d_in[21];
    const float* bm1 = (const float*)d_in[22];
    const float* Wm2 = (const float*)d_in[23];
    const float* bm2 = (const float*)d_in[24];
    float* out = (float*)d_out;

    // ---- workspace layout ----
    float* ws = (float*)d_ws;
    float* h       = ws;                                 // BL*Dm f32
    float* tmp     = h + (size_t)BL * Dm;                // BL*Dm f32
    float* qkvb    = tmp + (size_t)BL * Dm;              // NLAY*1536
    float* partial = qkvb + NLAY * QKVLD;                // (unused, kept for layout)
    float* mlp_t   = partial + (size_t)Bb * 6 * Dm;      // (unused, kept for layout)
    int* dr        = (int*)(mlp_t + Bb * Mm);            // B*L
    uchar* didx8   = (uchar*)(dr + Bb * Lq);             // B*L*L bytes
    short* hb      = (short*)(didx8 + (size_t)Bb * Lq * Lq); // BL*Dm
    short* Qb      = hb + (size_t)BL * Dm;               // BL*Dm
    short* Zb      = Qb + (size_t)BL * Dm;               // BL*Dm
    short* ffb     = Zb + (size_t)BL * Dm;               // BL*Ff
    short* Wt_all  = ffb + (size_t)BL * Ff;              // NLAY*WLAY
    const size_t WLAY = 4ull * Dm * Dm + (size_t)Dm * Ff + (size_t)Ff * Dm;
    short* Wm1T    = Wt_all + NLAY * WLAY;               // Mm*Dm
    short* Ke      = Wm1T + (size_t)Mm * Dm;             // 32*KeROWS*64
    short* Vet     = Ke + (size_t)Bb * Hh * KeROWS * Kk; // 32*64*Lq

    prologue_all<<<10578, 256, 0, stream>>>(ct, cellemb, dist, de, bq, bk, bv,
                                            Wq, Wk, Wv, Wo, W1, W2, Wm1,
                                            h, hb, didx8, dr, qkvb, Ke, Wt_all, Wm1T);

    dim3 gQKV(QKVLD / 64, BL / 32);      // 24 x 48, 128 thr (KW=2)
    dim3 gD(Dm / 32, BL / 32);           // 16 x 48
    dim3 gF(Ff / 64, BL / 32);           // 32 x 48

    for (int l = 0; l < NLAY; ++l) {
        short* base = Wt_all + l * WLAY;
        short* WoT = base + 3 * Dm * Dm;
        short* W1T = base + 4 * Dm * Dm;
        short* W2T = base + 4 * Dm * Dm + Dm * Ff;

        qkv_gemm<<<gQKV, 128, 0, stream>>>(hb, base, qkvb + l * QKVLD, dr, de, Qb, Ke, Vet);
        attn_fused<<<768, 512, 0, stream>>>(Qb, Ke, Vet, didx8, dr, de, Zb);

        mfma_gemm<0, 0, Dm, 2, 2><<<gD, 128, 0, stream>>>(Zb, WoT, bo + l * Dm, tmp, Dm, Dm, Dm);
        add_ln_kernel<<<BL, 128, 0, stream>>>(h, hb, tmp, g1 + l * Dm, be1 + l * Dm);

        mfma_gemm<1, 1, Dm, 4, 2><<<gF, 128, 0, stream>>>(hb, W1T, b1 + l * Ff, ffb, Dm, Dm, Ff);
        mfma_gemm<0, 0, Ff, 2, 4><<<gD, 256, 0, stream>>>(ffb, W2T, b2 + l * Dm, tmp, Ff, Ff, Dm);
        add_ln_kernel<<<BL, 128, 0, stream>>>(h, hb, tmp, g2 + l * Dm, be2 + l * Dm);
    }

    head_all<<<Bb, 256, 0, stream>>>(h, mask, Wm1T, bm1, Wm2, bm2, out);
}

// Round 15
// 234.202 us; speedup vs baseline: 1.0695x; 1.0695x over previous
//
#include <hip/hip_runtime.h>
#include <math.h>

#define Bb 4
#define Lq 384
#define Dm 512
#define Hh 8
#define Kk 64
#define Ff 2048
#define Mm 512
#define NLAY 2
#define NDb 15
#define BL (Bb*Lq)
#define QKVLD 1536
#define KeROWS 448          // 384 keys + 15 de0 rows + zero pad
#define EP 460              // E LDS pitch (dwords): 460%32=12 -> conflict-light
#define PPs 920             // P LDS pitch (shorts), aliases E rows
#define LWP 17              // lw pitch (floats)
#define QR 16               // q-rows per attn block

typedef __attribute__((ext_vector_type(8))) short bfrag;
typedef __attribute__((ext_vector_type(4))) float f32x4;
typedef __attribute__((ext_vector_type(4))) short short4v;
typedef __attribute__((ext_vector_type(2))) unsigned int uint2v;
typedef unsigned int uint;
typedef unsigned char uchar;

__device__ __forceinline__ short f2b(float f) {
    unsigned u = __builtin_bit_cast(unsigned, f);
    unsigned r = (u + 0x7fffu + ((u >> 16) & 1u)) >> 16;
    return (short)r;
}
__device__ __forceinline__ float b2f(short s) {
    unsigned u = ((unsigned)(unsigned short)s) << 16;
    return __builtin_bit_cast(float, u);
}

// =============== prologue mega-kernel (all independent prep work) ===============
__device__ __forceinline__ void tile_tr(const float* __restrict__ src, short* __restrict__ dst,
                                        int Kd, int N, int t, int tx, int ty) {
    __shared__ float ts[32][33];
    int nt = t % (N / 32), kt = t / (N / 32);
    int n0 = nt * 32, k0 = kt * 32;
    for (int i = ty; i < 32; i += 8) ts[i][tx] = src[(size_t)(k0 + i) * N + n0 + tx];
    __syncthreads();
    for (int i = ty; i < 32; i += 8) dst[(size_t)(n0 + i) * Kd + k0 + tx] = f2b(ts[tx][i]);
}

__global__ __launch_bounds__(256) void prologue_all(
        const int* __restrict__ ct, const float* __restrict__ cell_emb,
        const float* __restrict__ dist, const float* __restrict__ de,
        const float* __restrict__ bq, const float* __restrict__ bk, const float* __restrict__ bv,
        const float* __restrict__ Wq, const float* __restrict__ Wk,
        const float* __restrict__ Wv, const float* __restrict__ Wo,
        const float* __restrict__ W1, const float* __restrict__ W2,
        const float* __restrict__ Wm1,
        float* __restrict__ h, short* __restrict__ hb,
        uchar* __restrict__ didx8, int* __restrict__ dr, float* __restrict__ qkvb,
        short* __restrict__ Ke, short* __restrict__ Wt_all, short* __restrict__ Wm1T) {
    const size_t WLAY = 4ull * Dm * Dm + (size_t)Dm * Ff + (size_t)Ff * Dm;
    int blk = blockIdx.x, tid = threadIdx.x;
    if (blk < 576) {                        // didx: 4 elems/thread, packed bytes
        int i = blk * 256 + tid;
        f32x4 d = *(const f32x4*)(dist + (size_t)i * 4);
        uint r = 0;
#pragma unroll
        for (int c = 0; c < 4; ++c) {
            int cnt = 0;
#pragma unroll
            for (int q = 1; q <= 14; ++q) cnt += (float)(10 * q) < d[c] ? 1 : 0;
            r |= (uint)cnt << (8 * c);
        }
        ((uint*)didx8)[i] = r;
    } else if (blk < 582) {                 // dr (from dist[b][0][x] directly)
        int i = (blk - 576) * 256 + tid;
        if (i < BL) {
            int b = i / Lq, x = i % Lq;
            float d = dist[(size_t)b * Lq * Lq + x];
            int c = 0;
#pragma unroll
            for (int q = 1; q <= 14; ++q) c += (float)(10 * q) < d ? 1 : 0;
            dr[i] = c;
        }
    } else if (blk < 3654) {                // embed
        int i = (blk - 582) * 256 + tid;
        int row = i / Dm, d = i % Dm;
        float v = cell_emb[ct[row] * Dm + d];
        h[i] = v;
        hb[i] = f2b(v);
    } else if (blk < 3666) {                // qkv bias concat
        int i = (blk - 3654) * 256 + tid;
        int l = i / QKVLD, c = i % QKVLD;
        float v = (c < Dm) ? bq[l * Dm + c] : (c < 2 * Dm) ? bk[l * Dm + c - Dm] : bv[l * Dm + c - 2 * Dm];
        qkvb[i] = v;
    } else if (blk < 4178) {                // Ke tail: de0 rows + zeros
        int i = (blk - 3666) * 256 + tid;   // 32*64*64
        int k = i & 63, rr = (i >> 6) & 63, z = i >> 12;
        short v = (rr < NDb) ? f2b(de[rr * Kk + k]) : (short)0;
        Ke[((size_t)z * KeROWS + Lq + rr) * Kk + k] = v;
    } else {                                // weight transposes
        int idx = blk - 4178;
        int tx = tid & 31, ty = tid >> 5;
        if (idx < 2048) {
            int m4 = idx >> 9, rem = idx & 511, l = rem >> 8, t = rem & 255;
            const float* src = (m4 == 0 ? Wq : m4 == 1 ? Wk : m4 == 2 ? Wv : Wo) + (size_t)l * Dm * Dm;
            tile_tr(src, Wt_all + l * WLAY + (size_t)m4 * Dm * Dm, Dm, Dm, t, tx, ty);
        } else if (idx < 4096) {
            int rem = idx - 2048, l = rem >> 10, t = rem & 1023;
            tile_tr(W1 + (size_t)l * Dm * Ff, Wt_all + l * WLAY + 4ull * Dm * Dm, Dm, Ff, t, tx, ty);
        } else if (idx < 6144) {
            int rem = idx - 4096, l = rem >> 10, t = rem & 1023;
            tile_tr(W2 + (size_t)l * Ff * Dm, Wt_all + l * WLAY + 4ull * Dm * Dm + (size_t)Dm * Ff, Ff, Dm, t, tx, ty);
        } else {
            tile_tr(Wm1, Wm1T, Dm, Mm, idx - 6144, tx, ty);
        }
    }
}

// =============== QKV GEMM (32x64 tile, 2-wave K-split) + fused K/V prep ===============
// Vet (V^T) stores are v-packed: the 4 accumulator v-values are consecutive x,
// so one short4v (8B) store replaces 4 scattered 2B stores.
__global__ __launch_bounds__(128) void qkv_gemm(const short* __restrict__ A,
                                                const short* __restrict__ Bt,
                                                const float* __restrict__ bias,
                                                const int* __restrict__ dr,
                                                const float* __restrict__ de,
                                                short* __restrict__ Qb,
                                                short* __restrict__ Ke,
                                                short* __restrict__ Vet) {
    const int tid = threadIdx.x;
    const int wave = tid >> 6, lane = tid & 63;
    const int row0 = blockIdx.y * 32, col0 = blockIdx.x * 64;
    const int r = lane & 15, g = lane >> 4;
    const int kbase = wave * (Dm / 2);
    __shared__ float red[64][33];
    f32x4 acc[2][4] = {};
#pragma unroll 4
    for (int k0 = 0; k0 < Dm / 2; k0 += 32) {
        bfrag a[2], b[4];
#pragma unroll
        for (int i = 0; i < 2; ++i)
            a[i] = *(const bfrag*)(A + (size_t)(row0 + i * 16 + r) * Dm + kbase + k0 + g * 8);
#pragma unroll
        for (int j = 0; j < 4; ++j)
            b[j] = *(const bfrag*)(Bt + (size_t)(col0 + j * 16 + r) * Dm + kbase + k0 + g * 8);
#pragma unroll
        for (int i = 0; i < 2; ++i)
#pragma unroll
            for (int j = 0; j < 4; ++j)
                acc[i][j] = __builtin_amdgcn_mfma_f32_16x16x32_bf16(a[i], b[j], acc[i][j], 0, 0, 0);
    }
    if (wave == 1) {
#pragma unroll
        for (int i = 0; i < 2; ++i)
#pragma unroll
            for (int j = 0; j < 4; ++j)
#pragma unroll
                for (int v = 0; v < 4; ++v)
                    red[lane][(i * 4 + j) * 4 + v] = acc[i][j][v];
    }
    __syncthreads();
    if (wave != 0) return;
#pragma unroll
    for (int i = 0; i < 2; ++i)
#pragma unroll
        for (int j = 0; j < 4; ++j)
#pragma unroll
            for (int v = 0; v < 4; ++v)
                acc[i][j][v] += red[lane][(i * 4 + j) * 4 + v];
    const float* de2 = de + 2 * NDb * Kk;
    const float* de5 = de + 5 * NDb * Kk;
    if (col0 < 2 * Dm) {
        // ---- Q / K region: stores already coalesced in 32B runs ----
#pragma unroll
        for (int i = 0; i < 2; ++i)
#pragma unroll
            for (int v = 0; v < 4; ++v) {
                int row = row0 + i * 16 + g * 4 + v;
                int b = row / Lq, x = row - b * Lq;
                int dd = dr[row];
#pragma unroll
                for (int j = 0; j < 4; ++j) {
                    int col = col0 + j * 16 + r;
                    float val = acc[i][j][v] + bias[col];
                    if (col < Dm) {
                        Qb[(size_t)row * Dm + col] = f2b(val);
                    } else {
                        int k = col & 63, h2 = (col >> 6) & 7, z = b * Hh + h2;
                        Ke[((size_t)z * KeROWS + x) * Kk + k] = f2b(val + de2[dd * Kk + k]);
                    }
                }
            }
    } else {
        // ---- V region: v-packed 8B stores (4 consecutive x per thread) ----
        int h2 = (col0 >> 6) & 7;
#pragma unroll
        for (int i = 0; i < 2; ++i) {
            int rowb = row0 + i * 16 + g * 4;        // 32-row tile within one b
            int b = rowb / Lq;
            int x0 = rowb - b * Lq;
            int z = b * Hh + h2;
            int dd[4];
#pragma unroll
            for (int v = 0; v < 4; ++v) dd[v] = dr[rowb + v];
#pragma unroll
            for (int j = 0; j < 4; ++j) {
                int k = j * 16 + r;                  // col0 is a multiple of 64
                float bc = bias[col0 + j * 16 + r];
                short4v pk4;
#pragma unroll
                for (int v = 0; v < 4; ++v)
                    pk4[v] = f2b(acc[i][j][v] + bc + de5[dd[v] * Kk + k]);
                *(short4v*)(Vet + ((size_t)z * Kk + k) * Lq + x0) = pk4;
            }
        }
    }
}

// =============== fused flash attention (8 waves, per 16 q-rows x one (b,h)) ===============
// 768 blocks x 512 thr; XCD x = n&7 owns z in {4x..4x+3} -> Ke/Vet L2-resident.
__global__ __launch_bounds__(512) void attn_fused(const short* __restrict__ Qb,
                                                  const short* __restrict__ Ke,
                                                  const short* __restrict__ Vet,
                                                  const uchar* __restrict__ didx8,
                                                  const int* __restrict__ dr,
                                                  const float* __restrict__ de,
                                                  short* __restrict__ Zb) {
    const int n = blockIdx.x;
    const int xcd = n & 7, kblk = n >> 3;       // kblk in [0,96)
    const int z = xcd * 4 + (kblk & 3);
    const int qt = kblk >> 2;                   // [0,24) tiles of 16 rows
    const int b = z >> 3, hh = z & 7;
    const int tid = threadIdx.x;
    const int wave = tid >> 6, lane = tid & 63;
    const int r = lane & 15, g = lane >> 4;
    __shared__ float Ef[QR * EP];
    __shared__ float lw[QR * LWP];
    __shared__ float invrow[QR];
    __shared__ float pred[4][64][5];            // PV partial reduce, padded

    // ---- hoisted didx loads (packed uint8, 12B = 3x uint per thread) ----
    const int row = tid >> 5, s32 = tid & 31;
    const int grow = qt * QR + row;
    const uchar* dxp = didx8 + ((size_t)(b * Lq + grow)) * Lq + s32 * 12;
    uint w0 = *(const uint*)(dxp);
    uint w1 = *(const uint*)(dxp + 4);
    uint w2 = *(const uint*)(dxp + 8);

    // ---- phase 1: E = Q @ Ke^T into LDS (cols 384.. hold q.de0[j]) ----
    const short* Qbase = Qb + ((size_t)(b * Lq + qt * QR)) * Dm + hh * Kk;
    const short* Kbase = Ke + (size_t)z * KeROWS * Kk;
    f32x4 eacc[2][2] = {};
#pragma unroll
    for (int k0 = 0; k0 < Kk; k0 += 32) {
        bfrag a = *(const bfrag*)(Qbase + (size_t)r * Dm + k0 + g * 8);
#pragma unroll
        for (int t = 0; t < 2; ++t) {
            int ctile = wave + t * 8;
            if (ctile < 14) {
                bfrag bb[2];
#pragma unroll
                for (int i = 0; i < 2; ++i)
                    bb[i] = *(const bfrag*)(Kbase + (size_t)(ctile * 32 + i * 16 + r) * Kk + k0 + g * 8);
#pragma unroll
                for (int j = 0; j < 2; ++j)
                    eacc[t][j] = __builtin_amdgcn_mfma_f32_16x16x32_bf16(a, bb[j], eacc[t][j], 0, 0, 0);
            }
        }
    }
#pragma unroll
    for (int t = 0; t < 2; ++t) {
        int ctile = wave + t * 8;
        if (ctile < 14) {
#pragma unroll
            for (int j = 0; j < 2; ++j)
#pragma unroll
                for (int v = 0; v < 4; ++v)
                    Ef[(g * 4 + v) * EP + ctile * 32 + j * 16 + r] = eacc[t][j][v];
        }
    }
    __syncthreads();

    // ---- phase 2: softmax (32 threads per row, 12 keys each, reg-cached) ----
    float* Er = Ef + row * EP;
    uint dxw[3] = {w0, w1, w2};
    float sv[12];
    float mx = -1e30f;
#pragma unroll
    for (int u = 0; u < 3; ++u) {
        f32x4 ev = *(const f32x4*)(Er + s32 * 12 + u * 4);
        uint w = dxw[u];
#pragma unroll
        for (int c = 0; c < 4; ++c) {
            int dxv = (w >> (8 * c)) & 255;
            float s = ev[c] + Er[Lq + dxv];
            sv[u * 4 + c] = s;
            mx = fmaxf(mx, s);
        }
    }
    mx = fmaxf(mx, __shfl_xor(mx, 1));
    mx = fmaxf(mx, __shfl_xor(mx, 2));
    mx = fmaxf(mx, __shfl_xor(mx, 4));
    mx = fmaxf(mx, __shfl_xor(mx, 8));
    mx = fmaxf(mx, __shfl_xor(mx, 16));
    float sum = 0.f;
    float bins[NDb];
#pragma unroll
    for (int q = 0; q < NDb; ++q) bins[q] = 0.f;
#pragma unroll
    for (int u = 0; u < 3; ++u) {
        uint w = dxw[u];
#pragma unroll
        for (int c = 0; c < 4; ++c) {
            int dxv = (w >> (8 * c)) & 255;
            float e = __expf(sv[u * 4 + c] - mx);
            sv[u * 4 + c] = e;
            sum += e;
#pragma unroll
            for (int q = 0; q < NDb; ++q) bins[q] += (dxv == q) ? e : 0.f;
        }
    }
    sum += __shfl_xor(sum, 1);
    sum += __shfl_xor(sum, 2);
    sum += __shfl_xor(sum, 4);
    sum += __shfl_xor(sum, 8);
    sum += __shfl_xor(sum, 16);
#pragma unroll
    for (int q = 0; q < NDb; ++q) {
        bins[q] += __shfl_xor(bins[q], 1);
        bins[q] += __shfl_xor(bins[q], 2);
        bins[q] += __shfl_xor(bins[q], 4);
        bins[q] += __shfl_xor(bins[q], 8);
        bins[q] += __shfl_xor(bins[q], 16);
    }
    float inv = 1.0f / sum;
    if (s32 == 0) {
        invrow[row] = inv;
#pragma unroll
        for (int q = 0; q < NDb; ++q) lw[row * LWP + q] = bins[q];
    }
    uint pk[6];
#pragma unroll
    for (int i = 0; i < 6; ++i) {
        uint lo = (unsigned short)f2b(sv[2 * i] * inv);
        uint hi = (unsigned short)f2b(sv[2 * i + 1] * inv);
        pk[i] = lo | (hi << 16);
    }
    __syncthreads();   // all E reads done -> safe to overwrite with bf16 P
    uint* prow = (uint*)((short*)Ef + row * PPs + s32 * 12);
#pragma unroll
    for (int i = 0; i < 6; ++i) prow[i] = pk[i];
    __syncthreads();

    // ---- phase 3: PV K-split (pair w,w+4 -> cols [w4*16,w4*16+16)) ----
    const int half = wave >> 2, w4 = wave & 3;
    const short* Ps = (const short*)Ef;
    const short* brow = Vet + (size_t)z * Kk * Lq + (size_t)(w4 * 16 + r) * Lq;
    const int kv0 = half * (Lq / 2);
    f32x4 pacc = {};
#pragma unroll
    for (int k0 = 0; k0 < Lq / 2; k0 += 32) {
        bfrag bb = *(const bfrag*)(brow + kv0 + k0 + g * 8);
        bfrag a = *(const bfrag*)(Ps + (size_t)r * PPs + kv0 + k0 + g * 8);
        pacc = __builtin_amdgcn_mfma_f32_16x16x32_bf16(a, bb, pacc, 0, 0, 0);
    }
    if (half == 1) {
#pragma unroll
        for (int v = 0; v < 4; ++v) pred[w4][lane][v] = pacc[v];
    }
    __syncthreads();
    if (half == 1) return;
#pragma unroll
    for (int v = 0; v < 4; ++v) pacc[v] += pred[w4][lane][v];
    const float* de3 = de + 3 * NDb * Kk;
    const float* de4 = de + 4 * NDb * Kk;
    const int k = w4 * 16 + r;
    float d3[NDb];
#pragma unroll
    for (int q = 0; q < NDb; ++q) d3[q] = de3[q * Kk + k];
#pragma unroll
    for (int v = 0; v < 4; ++v) {
        int lrow = g * 4 + v;
        int gr = qt * QR + lrow;
        float wsv = 0.f;
#pragma unroll
        for (int q = 0; q < NDb; ++q) wsv += lw[lrow * LWP + q] * d3[q];
        int dd = dr[b * Lq + gr];
        float val = pacc[v] + wsv * invrow[lrow] + de4[dd * Kk + k];
        Zb[((size_t)(b * Lq + gr)) * Dm + hh * Kk + k] = f2b(val);
    }
}

// =============== generic MFMA GEMM with KW-wave K-split ===============
template <int ACT, int OUTBF, int KD, int CT, int KW>
__global__ __launch_bounds__(64 * KW) void mfma_gemm(const short* __restrict__ A,
                                                     const short* __restrict__ Bt,
                                                     const float* __restrict__ bias,
                                                     void* __restrict__ Cv,
                                                     int lda, int ldb, int ldc) {
    const int tid = threadIdx.x;
    const int wave = tid >> 6, lane = tid & 63;
    const int row0 = blockIdx.y * 32, col0 = blockIdx.x * (16 * CT);
    const int r = lane & 15, g = lane >> 4;
    const int KC = KD / KW;
    const int kbase = wave * KC;
    __shared__ float red[KW > 1 ? KW - 1 : 1][64][2 * CT * 4 + 1];
    f32x4 acc[2][CT] = {};
#pragma unroll 4
    for (int k0 = 0; k0 < KC; k0 += 32) {
        bfrag a[2], b[CT];
#pragma unroll
        for (int i = 0; i < 2; ++i)
            a[i] = *(const bfrag*)(A + (size_t)(row0 + i * 16 + r) * lda + kbase + k0 + g * 8);
#pragma unroll
        for (int j = 0; j < CT; ++j)
            b[j] = *(const bfrag*)(Bt + (size_t)(col0 + j * 16 + r) * ldb + kbase + k0 + g * 8);
#pragma unroll
        for (int i = 0; i < 2; ++i)
#pragma unroll
            for (int j = 0; j < CT; ++j)
                acc[i][j] = __builtin_amdgcn_mfma_f32_16x16x32_bf16(a[i], b[j], acc[i][j], 0, 0, 0);
    }
    if (KW > 1) {
        if (wave > 0) {
#pragma unroll
            for (int i = 0; i < 2; ++i)
#pragma unroll
                for (int j = 0; j < CT; ++j)
#pragma unroll
                    for (int v = 0; v < 4; ++v)
                        red[wave - 1][lane][(i * CT + j) * 4 + v] = acc[i][j][v];
        }
        __syncthreads();
        if (wave != 0) return;
#pragma unroll
        for (int w = 0; w < KW - 1; ++w)
#pragma unroll
            for (int i = 0; i < 2; ++i)
#pragma unroll
                for (int j = 0; j < CT; ++j)
#pragma unroll
                    for (int v = 0; v < 4; ++v)
                        acc[i][j][v] += red[w][lane][(i * CT + j) * 4 + v];
    }
#pragma unroll
    for (int i = 0; i < 2; ++i)
#pragma unroll
        for (int j = 0; j < CT; ++j)
#pragma unroll
            for (int v = 0; v < 4; ++v) {
                int row = row0 + i * 16 + g * 4 + v;
                int col = col0 + j * 16 + r;
                float val = acc[i][j][v] + bias[col];
                if (ACT == 1) val = 0.5f * val * (1.0f + erff(val * 0.7071067811865475f));
                if (OUTBF) ((short*)Cv)[(size_t)row * ldc + col] = f2b(val);
                else       ((float*)Cv)[(size_t)row * ldc + col] = val;
            }
}

// =============== residual add + LayerNorm (2 barriers, vectorized) ===============
__global__ __launch_bounds__(128) void add_ln_kernel(float* __restrict__ h,
                                                     short* __restrict__ hb,
                                                     const float* __restrict__ delta,
                                                     const float* __restrict__ g,
                                                     const float* __restrict__ be) {
    const int row = blockIdx.x, t = threadIdx.x;
    const int lane = t & 63, wid = t >> 6;
    __shared__ float red[4];
    f32x4 x = *(const f32x4*)(h + (size_t)row * Dm + t * 4);
    f32x4 d = *(const f32x4*)(delta + (size_t)row * Dm + t * 4);
    x = x + d;
    float s = x[0] + x[1] + x[2] + x[3];
#pragma unroll
    for (int o = 32; o >= 1; o >>= 1) s += __shfl_xor(s, o);
    if (lane == 0) red[wid] = s;
    __syncthreads();
    float mu = (red[0] + red[1]) * (1.0f / 512.0f);
    f32x4 dif;
    float vs = 0.f;
#pragma unroll
    for (int c = 0; c < 4; ++c) { dif[c] = x[c] - mu; vs += dif[c] * dif[c]; }
#pragma unroll
    for (int o = 32; o >= 1; o >>= 1) vs += __shfl_xor(vs, o);
    if (lane == 0) red[wid + 2] = vs;
    __syncthreads();
    float rstd = rsqrtf((red[2] + red[3]) * (1.0f / 512.0f) + 1e-5f);
    f32x4 gg = *(const f32x4*)(g + t * 4);
    f32x4 bb = *(const f32x4*)(be + t * 4);
    f32x4 y;
    short4v yb;
#pragma unroll
    for (int c = 0; c < 4; ++c) { y[c] = dif[c] * rstd * gg[c] + bb[c]; yb[c] = f2b(y[c]); }
    *(f32x4*)(h + (size_t)row * Dm + t * 4) = y;
    *(short4v*)(hb + (size_t)row * Dm + t * 4) = yb;
}

// =============== head ===============
__global__ __launch_bounds__(512) void pool_partial(const float* __restrict__ h,
                                                    const float* __restrict__ mask,
                                                    float* __restrict__ partial) {
    int c = blockIdx.x, b = blockIdx.y, d = threadIdx.x;
    float acc = 0.f;
#pragma unroll 8
    for (int i = 0; i < 64; ++i) {
        int l = c * 64 + i;
        acc += h[((size_t)(b * Lq + l)) * Dm + d] * mask[b * Lq + l];
    }
    partial[((size_t)(b * 6 + c)) * Dm + d] = acc;
}

__global__ __launch_bounds__(256) void head_mlp(const float* __restrict__ partial,
                                                const short* __restrict__ Wm1T,
                                                const float* __restrict__ bm1,
                                                const float* __restrict__ Wm2,
                                                float* __restrict__ mlp_t) {
    int w = blockIdx.x * 4 + (threadIdx.x >> 6);
    int lane = threadIdx.x & 63;
    int m = w >> 2, b = w & 3;
    const short* wr = Wm1T + (size_t)m * Dm;
    float acc = 0.f;
#pragma unroll
    for (int i = 0; i < 8; ++i) {
        int k = lane * 8 + i;
        float pool = 0.f;
#pragma unroll
        for (int c = 0; c < 6; ++c) pool += partial[((size_t)(b * 6 + c)) * Dm + k];
        acc += pool * b2f(wr[k]);
    }
#pragma unroll
    for (int off = 32; off >= 1; off >>= 1) acc += __shfl_xor(acc, off);
    if (lane == 0) mlp_t[b * Mm + m] = fmaxf(acc + bm1[m], 0.f) * Wm2[m];
}

__global__ __launch_bounds__(256) void final_kernel(const float* __restrict__ mlp_t,
                                                    const float* __restrict__ bm2,
                                                    float* __restrict__ out) {
    int b = blockIdx.x, t = threadIdx.x;
    int lane = t & 63, wid = t >> 6;
    __shared__ float red[4];
    float v = mlp_t[b * Mm + t] + mlp_t[b * Mm + 256 + t];
#pragma unroll
    for (int off = 32; off >= 1; off >>= 1) v += __shfl_xor(v, off);
    if (lane == 0) red[wid] = v;
    __syncthreads();
    if (t == 0) out[b] = red[0] + red[1] + red[2] + red[3] + bm2[0];
}

extern "C" void kernel_launch(void* const* d_in, const int* in_sizes, int n_in,
                              void* d_out, int out_size, void* d_ws, size_t ws_size,
                              hipStream_t stream) {
    const int* ct        = (const int*)d_in[0];
    const float* dist    = (const float*)d_in[1];
    const float* mask    = (const float*)d_in[2];
    const float* cellemb = (const float*)d_in[3];
    const float* de      = (const float*)d_in[4];
    const float* Wq = (const float*)d_in[5];
    const float* bq = (const float*)d_in[6];
    const float* Wk = (const float*)d_in[7];
    const float* bk = (const float*)d_in[8];
    const float* Wv = (const float*)d_in[9];
    const float* bv = (const float*)d_in[10];
    const float* Wo = (const float*)d_in[11];
    const float* bo = (const float*)d_in[12];
    const float* W1 = (const float*)d_in[13];
    const float* b1 = (const float*)d_in[14];
    const float* W2 = (const float*)d_in[15];
    const float* b2 = (const float*)d_in[16];
    const float* g1 = (const float*)d_in[17];
    const float* be1 = (const float*)d_in[18];
    const float* g2 = (const float*)d_in[19];
    const float* be2 = (const float*)d_in[20];
    const float* Wm1 = (const float*)d_in[21];
    const float* bm1 = (const float*)d_in[22];
    const float* Wm2 = (const float*)d_in[23];
    const float* bm2 = (const float*)d_in[24];
    float* out = (float*)d_out;

    // ---- workspace layout ----
    float* ws = (float*)d_ws;
    float* h       = ws;                                 // BL*Dm f32
    float* tmp     = h + (size_t)BL * Dm;                // BL*Dm f32
    float* qkvb    = tmp + (size_t)BL * Dm;              // NLAY*1536
    float* partial = qkvb + NLAY * QKVLD;                // Bb*6*Dm
    float* mlp_t   = partial + (size_t)Bb * 6 * Dm;      // Bb*Mm
    int* dr        = (int*)(mlp_t + Bb * Mm);            // B*L
    uchar* didx8   = (uchar*)(dr + Bb * Lq);             // B*L*L bytes
    short* hb      = (short*)(didx8 + (size_t)Bb * Lq * Lq); // BL*Dm
    short* Qb      = hb + (size_t)BL * Dm;               // BL*Dm
    short* Zb      = Qb + (size_t)BL * Dm;               // BL*Dm
    short* ffb     = Zb + (size_t)BL * Dm;               // BL*Ff
    short* Wt_all  = ffb + (size_t)BL * Ff;              // NLAY*WLAY
    const size_t WLAY = 4ull * Dm * Dm + (size_t)Dm * Ff + (size_t)Ff * Dm;
    short* Wm1T    = Wt_all + NLAY * WLAY;               // Mm*Dm
    short* Ke      = Wm1T + (size_t)Mm * Dm;             // 32*KeROWS*64
    short* Vet     = Ke + (size_t)Bb * Hh * KeROWS * Kk; // 32*64*Lq

    prologue_all<<<10578, 256, 0, stream>>>(ct, cellemb, dist, de, bq, bk, bv,
                                            Wq, Wk, Wv, Wo, W1, W2, Wm1,
                                            h, hb, didx8, dr, qkvb, Ke, Wt_all, Wm1T);

    dim3 gQKV(QKVLD / 64, BL / 32);      // 24 x 48, 128 thr (KW=2)
    dim3 gD(Dm / 32, BL / 32);           // 16 x 48
    dim3 gF(Ff / 64, BL / 32);           // 32 x 48

    for (int l = 0; l < NLAY; ++l) {
        short* base = Wt_all + l * WLAY;
        short* WoT = base + 3 * Dm * Dm;
        short* W1T = base + 4 * Dm * Dm;
        short* W2T = base + 4 * Dm * Dm + Dm * Ff;

        qkv_gemm<<<gQKV, 128, 0, stream>>>(hb, base, qkvb + l * QKVLD, dr, de, Qb, Ke, Vet);
        attn_fused<<<768, 512, 0, stream>>>(Qb, Ke, Vet, didx8, dr, de, Zb);

        mfma_gemm<0, 0, Dm, 2, 2><<<gD, 128, 0, stream>>>(Zb, WoT, bo + l * Dm, tmp, Dm, Dm, Dm);
        add_ln_kernel<<<BL, 128, 0, stream>>>(h, hb, tmp, g1 + l * Dm, be1 + l * Dm);

        mfma_gemm<1, 1, Dm, 4, 2><<<gF, 128, 0, stream>>>(hb, W1T, b1 + l * Ff, ffb, Dm, Dm, Ff);
        mfma_gemm<0, 0, Ff, 2, 4><<<gD, 256, 0, stream>>>(ffb, W2T, b2 + l * Dm, tmp, Ff, Ff, Dm);
        add_ln_kernel<<<BL, 128, 0, stream>>>(h, hb, tmp, g2 + l * Dm, be2 + l * Dm);
    }

    pool_partial<<<dim3(6, Bb), 512, 0, stream>>>(h, mask, partial);
    head_mlp<<<512, 256, 0, stream>>>(partial, Wm1T, bm1, Wm2, mlp_t);
    final_kernel<<<Bb, 256, 0, stream>>>(mlp_t, bm2, out);
}